// Round 3
// baseline (1365.341 us; speedup 1.0000x reference)
//
#include <hip/hip_runtime.h>

// MHA forward: B=4, L=2048, E=1024, H=16, D=64, causal, returns (out, attn_probs)

typedef __attribute__((ext_vector_type(8))) short short8;
typedef __attribute__((ext_vector_type(4))) float f32x4;

#define MFMA_BF16(a,b,c) __builtin_amdgcn_mfma_f32_16x16x32_bf16((a),(b),(c),0,0,0)

#define GLDS(gp, lp) __builtin_amdgcn_global_load_lds( \
    (const __attribute__((address_space(1))) unsigned int*)(gp), \
    (__attribute__((address_space(3))) unsigned int*)(lp), 16, 0, 0)

__device__ __forceinline__ unsigned short f2bf(float f) {
    union { float f; unsigned u; } v; v.f = f;
    return (unsigned short)((v.u + 0x7FFFu + ((v.u >> 16) & 1u)) >> 16);
}

// 0.125 (head-dim scale) * log2(e): folded into q at QKV-GEMM epilogue
#define QK_SCALE 0.18033688011112042f

// ---------------- cast x -> bf16 ----------------
__global__ __launch_bounds__(256) void k_cast(const float* __restrict__ src,
                                              unsigned short* __restrict__ dst, int n8) {
    int i = blockIdx.x * 256 + threadIdx.x;
    if (i >= n8) return;
    const float4* s = (const float4*)src + (size_t)i * 2;
    float4 a = s[0], b = s[1];
    short8 o;
    o[0] = f2bf(a.x); o[1] = f2bf(a.y); o[2] = f2bf(a.z); o[3] = f2bf(a.w);
    o[4] = f2bf(b.x); o[5] = f2bf(b.y); o[6] = f2bf(b.z); o[7] = f2bf(b.w);
    ((short8*)dst)[i] = o;
}

// ---------------- transpose + cast weights: src[R][C] f32 -> dst[C][R] bf16 ----------------
__global__ __launch_bounds__(256) void k_transpose_cast(const float* __restrict__ src,
                                                        unsigned short* __restrict__ dst,
                                                        int R, int C) {
    __shared__ unsigned short t[64][72];
    int c0 = blockIdx.x * 64, r0 = blockIdx.y * 64;
    int tid = threadIdx.x;
    int rl = tid >> 2, cs = (tid & 3) * 16;
    const float* sp = src + (size_t)(r0 + rl) * C + c0 + cs;
    #pragma unroll
    for (int j = 0; j < 16; j += 4) {
        float4 v = *(const float4*)(sp + j);
        t[rl][cs + j + 0] = f2bf(v.x);
        t[rl][cs + j + 1] = f2bf(v.y);
        t[rl][cs + j + 2] = f2bf(v.z);
        t[rl][cs + j + 3] = f2bf(v.w);
    }
    __syncthreads();
    int clq = tid >> 2, rs = (tid & 3) * 16;
    short8 o0, o1;
    #pragma unroll
    for (int j = 0; j < 8; ++j) o0[j] = (short)t[rs + j][clq];
    #pragma unroll
    for (int j = 0; j < 8; ++j) o1[j] = (short)t[rs + 8 + j][clq];
    unsigned short* dp = dst + (size_t)(c0 + clq) * R + r0 + rs;
    *(short8*)dp = o0;
    *(short8*)(dp + 8) = o1;
}

// ---------------- QKV GEMM (+overlapped probs upper-triangle zero-fill) ----------------
// blocks x<24: GEMM [8192x1024]x[1024x3072]; blocks x in 24..31: zero-fill
// probs[bh][r][c] for c >= (r/64+1)*64 (region attn never writes).
__global__ __launch_bounds__(256) void k_gemm_qkv(
    const unsigned short* __restrict__ A,    // xb [8192][1024]
    const unsigned short* __restrict__ Bt,   // wqkvT [3072][1024]
    const float* __restrict__ bias,          // [3072]
    unsigned short* __restrict__ qb,
    unsigned short* __restrict__ kb,
    unsigned short* __restrict__ vb,
    float* __restrict__ probs)               // [64][2048][2048]
{
    if (blockIdx.x >= 24) {                  // ---- zero-fill path ----
        const int c = blockIdx.x - 24;       // 0..7
        const int bh = blockIdx.y;           // 0..63
        const int r = threadIdx.x >> 2;      // 0..63 row within tile
        const int c4 = (threadIdx.x & 3) * 4;
        const float4 z = make_float4(0.f, 0.f, 0.f, 0.f);
        for (int tt = c; tt < 32; tt += 8) { // row-tile index, interleaved for balance
            float* rp = probs + ((size_t)bh * 2048 + tt * 64 + r) * 2048;
            for (int cc = (tt + 1) * 64 + c4; cc < 2048; cc += 16)
                *(float4*)&rp[cc] = z;
        }
        return;
    }

    __shared__ unsigned short As[128 * 32];
    __shared__ unsigned short Bs[128 * 32];
    const int m0 = blockIdx.y * 128, n0 = blockIdx.x * 128;
    const int tid = threadIdx.x, w = tid >> 6, l = tid & 63;
    const int wm = w >> 1, wn = w & 1;
    const int g = l >> 4, cl = l & 15;
    const int srow = w * 16 + (l >> 2);
    const int soff = (l & 3) * 8;
    f32x4 acc[4][4] = {};

    for (int k0 = 0; k0 < 1024; k0 += 32) {
        __syncthreads();
        #pragma unroll
        for (int c = 0; c < 2; ++c) {
            GLDS(A  + (size_t)(m0 + c * 64 + srow) * 1024 + k0 + soff, &As[(c * 64 + w * 16) * 32]);
            GLDS(Bt + (size_t)(n0 + c * 64 + srow) * 1024 + k0 + soff, &Bs[(c * 64 + w * 16) * 32]);
        }
        __syncthreads();
        short8 af[4], bfr[4];
        #pragma unroll
        for (int i = 0; i < 4; ++i) af[i]  = *(const short8*)&As[(wm * 64 + i * 16 + cl) * 32 + g * 8];
        #pragma unroll
        for (int i = 0; i < 4; ++i) bfr[i] = *(const short8*)&Bs[(wn * 64 + i * 16 + cl) * 32 + g * 8];
        #pragma unroll
        for (int mi = 0; mi < 4; ++mi)
            #pragma unroll
            for (int ni = 0; ni < 4; ++ni)
                acc[mi][ni] = MFMA_BF16(af[mi], bfr[ni], acc[mi][ni]);
    }
    #pragma unroll
    for (int ni = 0; ni < 4; ++ni) {
        int col = n0 + wn * 64 + ni * 16 + cl;
        int which = col >> 10, h = (col >> 6) & 15, d = col & 63;
        unsigned short* dst = which == 0 ? qb : (which == 1 ? kb : vb);
        float bv = bias[col];
        float sc = (which == 0) ? QK_SCALE : 1.0f;   // fold softmax scale into q
        #pragma unroll
        for (int mi = 0; mi < 4; ++mi) {
            #pragma unroll
            for (int i = 0; i < 4; ++i) {
                int row = m0 + wm * 64 + mi * 16 + g * 4 + i;
                int b = row >> 11, ll = row & 2047;
                dst[((size_t)(b * 16 + h) * 2048 + ll) * 64 + d] = f2bf((acc[mi][ni][i] + bv) * sc);
            }
        }
    }
}

// ---------------- out projection GEMM: ctx[8192][1024] x woutT -> out f32 ----------------
__global__ __launch_bounds__(256) void k_gemm_out(
    const unsigned short* __restrict__ A,    // ctx [8192][1024]
    const unsigned short* __restrict__ Bt,   // woutT [1024][1024]
    const float* __restrict__ bias,          // [1024]
    float* __restrict__ out)
{
    __shared__ unsigned short As[128 * 32];
    __shared__ unsigned short Bs[128 * 32];
    const int m0 = blockIdx.y * 128, n0 = blockIdx.x * 128;
    const int tid = threadIdx.x, w = tid >> 6, l = tid & 63;
    const int wm = w >> 1, wn = w & 1;
    const int g = l >> 4, cl = l & 15;
    const int srow = w * 16 + (l >> 2);
    const int soff = (l & 3) * 8;
    f32x4 acc[4][4] = {};

    for (int k0 = 0; k0 < 1024; k0 += 32) {
        __syncthreads();
        #pragma unroll
        for (int c = 0; c < 2; ++c) {
            GLDS(A  + (size_t)(m0 + c * 64 + srow) * 1024 + k0 + soff, &As[(c * 64 + w * 16) * 32]);
            GLDS(Bt + (size_t)(n0 + c * 64 + srow) * 1024 + k0 + soff, &Bs[(c * 64 + w * 16) * 32]);
        }
        __syncthreads();
        short8 af[4], bfr[4];
        #pragma unroll
        for (int i = 0; i < 4; ++i) af[i]  = *(const short8*)&As[(wm * 64 + i * 16 + cl) * 32 + g * 8];
        #pragma unroll
        for (int i = 0; i < 4; ++i) bfr[i] = *(const short8*)&Bs[(wn * 64 + i * 16 + cl) * 32 + g * 8];
        #pragma unroll
        for (int mi = 0; mi < 4; ++mi)
            #pragma unroll
            for (int ni = 0; ni < 4; ++ni)
                acc[mi][ni] = MFMA_BF16(af[mi], bfr[ni], acc[mi][ni]);
    }
    #pragma unroll
    for (int ni = 0; ni < 4; ++ni) {
        int col = n0 + wn * 64 + ni * 16 + cl;
        float bv = bias[col];
        #pragma unroll
        for (int mi = 0; mi < 4; ++mi) {
            #pragma unroll
            for (int i = 0; i < 4; ++i) {
                int row = m0 + wm * 64 + mi * 16 + g * 4 + i;
                out[(size_t)row * 1024 + col] = acc[mi][ni][i] + bv;
            }
        }
    }
}

// ---------------- attention ----------------
// Stage a 64x64 bf16 tile (row-major, stride 64) into linear LDS [64][64] via
// global_load_lds, with the read-side XOR swizzle pre-applied to the GLOBAL
// source (rule #21 both-sides): LDS[row][chunk c] = G[row][c ^ (row&7)].
__device__ __forceinline__ void stage_qk(const unsigned short* gbase,
                                         unsigned short* lds, int w, int l) {
    const int lr = l >> 3;                 // 0..7 (row within the 8-row stripe)
    const int lc = (l & 7) ^ lr;           // pre-swizzled global chunk
    #pragma unroll
    for (int c = 0; c < 2; ++c) {
        const int r0 = (w * 2 + c) * 8;    // stripe base row (wave-uniform)
        GLDS(gbase + (size_t)(r0 + lr) * 64 + (lc << 3), lds + r0 * 64);
    }
}

__global__ __launch_bounds__(256, 4) void k_attn(
    const unsigned short* __restrict__ qb,
    const unsigned short* __restrict__ kb,
    const unsigned short* __restrict__ vb,
    float* __restrict__ probs,               // [64][2048][2048]
    unsigned short* __restrict__ ctx)        // [4][2048][1024] bf16
{
    __shared__ unsigned short Ks[2][64 * 64];    // 16 KB, double-buffered
    __shared__ unsigned short QV[64 * 64];       // 8 KB: Q tile, reused as Vt after frag load
    __shared__ unsigned short Ps[4 * 16 * 64];   // 8 KB, per-wave [16][64] chunk-XOR
    // total 32 KB -> 4 blocks/CU

    // XCD-aware swizzle (2048 blocks % 8 == 0 -> bijective): XCD j serves
    // bh j*8..j*8+7 (K/V working set ~2MB, fits 4MB L2); qt descending so
    // longest blocks launch first.
    const int lid = blockIdx.y * 32 + blockIdx.x;
    const int nl  = (lid & 7) * 256 + (lid >> 3);
    const int qt  = 31 - (nl & 31);          // 0..31
    const int bh  = nl >> 5;                 // 0..63

    const int tid = threadIdx.x;
    const int w = tid >> 6, l = tid & 63;
    const int g = l >> 4, cl = l & 15;

    const unsigned short* Qg = qb + (size_t)bh * (2048 * 64);
    const unsigned short* Kg = kb + (size_t)bh * (2048 * 64);
    const unsigned short* Vg = vb + (size_t)bh * (2048 * 64);

    stage_qk(Qg + (size_t)qt * (64 * 64), QV, w, l);
    stage_qk(Kg, Ks[0], w, l);
    __syncthreads();

    const int qr = w * 16 + cl;              // this lane's Q row for the A-frag
    short8 aq0 = *(const short8*)&QV[qr * 64 + ((g ^ (qr & 7)) << 3)];
    short8 aq1 = *(const short8*)&QV[qr * 64 + (((g + 4) ^ (qr & 7)) << 3)];

    // ---- pass 1: row sums of exp2 (q pre-scaled; no max; reduce deferred) ----
    f32x4 lpart = {0.f, 0.f, 0.f, 0.f};
    for (int kt = 0; kt <= qt; ++kt) {
        const unsigned short* K = Ks[kt & 1];
        if (kt < qt) {
            stage_qk(Kg + (size_t)(kt + 1) * (64 * 64), Ks[(kt & 1) ^ 1], w, l);
            #pragma unroll
            for (int kf = 0; kf < 4; ++kf) {
                int r = kf * 16 + cl;
                short8 b0 = *(const short8*)&K[r * 64 + ((g ^ (r & 7)) << 3)];
                short8 b1 = *(const short8*)&K[r * 64 + (((g + 4) ^ (r & 7)) << 3)];
                f32x4 acc = {0.f, 0.f, 0.f, 0.f};
                acc = MFMA_BF16(aq0, b0, acc);
                acc = MFMA_BF16(aq1, b1, acc);
                #pragma unroll
                for (int i = 0; i < 4; ++i)
                    lpart[i] += __builtin_amdgcn_exp2f(acc[i]);
            }
        } else {
            #pragma unroll
            for (int kf = 0; kf < 4; ++kf) {
                int r = kf * 16 + cl;
                short8 b0 = *(const short8*)&K[r * 64 + ((g ^ (r & 7)) << 3)];
                short8 b1 = *(const short8*)&K[r * 64 + (((g + 4) ^ (r & 7)) << 3)];
                f32x4 acc = {0.f, 0.f, 0.f, 0.f};
                acc = MFMA_BF16(aq0, b0, acc);
                acc = MFMA_BF16(aq1, b1, acc);
                #pragma unroll
                for (int i = 0; i < 4; ++i) {
                    float e = __builtin_amdgcn_exp2f(acc[i]);
                    lpart[i] += (r > w * 16 + g * 4 + i) ? 0.f : e;
                }
            }
        }
        __syncthreads();
    }

    f32x4 lr;   // -log2(rowsum): p = exp2(acc + lr)
    #pragma unroll
    for (int i = 0; i < 4; ++i) {
        float s = lpart[i];
        s += __shfl_xor(s, 1);
        s += __shfl_xor(s, 2);
        s += __shfl_xor(s, 4);
        s += __shfl_xor(s, 8);
        lr[i] = -__log2f(s);
    }

    // ---- pass 2: probs + PV ----
    stage_qk(Kg, Ks[0], w, l);
    // V ownership: thread t holds k-pair (t&31), d-chunk (t>>5).
    const int vkp = tid & 31;
    const int vd0 = (tid >> 5) * 8;
    short8 va  = *(const short8*)(Vg + (size_t)(2 * vkp) * 64 + vd0);
    short8 vb8 = *(const short8*)(Vg + (size_t)(2 * vkp + 1) * 64 + vd0);
    __syncthreads();

    f32x4 cacc[4] = {};
    unsigned int* Vt32 = (unsigned int*)QV;

    for (int kt = 0; kt <= qt; ++kt) {
        const unsigned short* K = Ks[kt & 1];
        const bool last = (kt == qt);
        if (!last) stage_qk(Kg + (size_t)(kt + 1) * (64 * 64), Ks[(kt & 1) ^ 1], w, l);

        // write V(kt) transposed: Vt[d][k], packed u32 (2 k's), 2-way banks
        #pragma unroll
        for (int j = 0; j < 8; ++j) {
            unsigned int pk = (unsigned int)(unsigned short)va[j]
                            | ((unsigned int)(unsigned short)vb8[j] << 16);
            Vt32[(vd0 + j) * 32 + (((vkp >> 2) ^ j) << 2) + (vkp & 3)] = pk;
        }
        if (!last) {  // prefetch V(kt+1); latency hidden under QK phase
            va  = *(const short8*)(Vg + (size_t)((kt + 1) * 64 + 2 * vkp) * 64 + vd0);
            vb8 = *(const short8*)(Vg + (size_t)((kt + 1) * 64 + 2 * vkp + 1) * 64 + vd0);
        }

        // QK + exp2(+lr) + inline probs stores + Ps (bf16, chunk-XOR layout)
        size_t prow = ((size_t)bh * 2048 + qt * 64 + w * 16 + g * 4) * 2048 + kt * 64;
        #pragma unroll
        for (int kf = 0; kf < 4; ++kf) {
            int r = kf * 16 + cl;
            short8 b0 = *(const short8*)&K[r * 64 + ((g ^ (r & 7)) << 3)];
            short8 b1 = *(const short8*)&K[r * 64 + (((g + 4) ^ (r & 7)) << 3)];
            f32x4 acc = {0.f, 0.f, 0.f, 0.f};
            acc = MFMA_BF16(aq0, b0, acc);
            acc = MFMA_BF16(aq1, b1, acc);
            #pragma unroll
            for (int i = 0; i < 4; ++i) {
                float p = __builtin_amdgcn_exp2f(acc[i] + lr[i]);
                if (last && r > w * 16 + g * 4 + i) p = 0.f;
                probs[prow + (size_t)i * 2048 + kf * 16 + cl] = p;
                int rr = g * 4 + i;
                int scol = (((2 * kf + (cl >> 3)) ^ (rr & 7)) << 3) + (cl & 7);
                Ps[(w * 16 + rr) * 64 + scol] = f2bf(p);
            }
        }
        __syncthreads();   // Ps + Vt visible

        #pragma unroll
        for (int kk = 0; kk < 2; ++kk) {
            short8 pa = *(const short8*)&Ps[(w * 16 + cl) * 64 + (((kk * 4 + g) ^ (cl & 7)) << 3)];
            #pragma unroll
            for (int df = 0; df < 4; ++df) {
                int vr = df * 16 + cl;
                short8 vf = *(const short8*)&QV[vr * 64 + (((kk * 4 + g) ^ (vr & 7)) << 3)];
                cacc[df] = MFMA_BF16(pa, vf, cacc[df]);
            }
        }
        __syncthreads();   // PV reads done before next tile's Vt/Ps/Ks writes
    }

    // write context bf16 [B][L][E]  (upper-triangle probs zeros were written
    // by k_gemm_qkv's fill blocks)
    {
        const int b = bh >> 4, h = bh & 15;
        #pragma unroll
        for (int df = 0; df < 4; ++df) {
            #pragma unroll
            for (int i = 0; i < 4; ++i) {
                int row = qt * 64 + w * 16 + g * 4 + i;
                ctx[((size_t)(b * 2048 + row)) * 1024 + h * 64 + df * 16 + cl] = f2bf(cacc[df][i]);
            }
        }
    }
}

extern "C" void kernel_launch(void* const* d_in, const int* in_sizes, int n_in,
                              void* d_out, int out_size, void* d_ws, size_t ws_size,
                              hipStream_t stream) {
    const float* x     = (const float*)d_in[0];
    const float* w_qkv = (const float*)d_in[1];
    const float* b_qkv = (const float*)d_in[2];
    const float* w_out = (const float*)d_in[3];
    const float* b_out = (const float*)d_in[4];

    float* out   = (float*)d_out;
    float* probs = out + (size_t)8192 * 1024;   // out first, then attn_probs

    char* ws = (char*)d_ws;
    unsigned short* xb    = (unsigned short*)(ws);                 // 16,777,216 B
    unsigned short* wqkvT = (unsigned short*)(ws + 16777216);      //  6,291,456 B
    unsigned short* woutT = (unsigned short*)(ws + 23068672);      //  2,097,152 B
    unsigned short* qb    = (unsigned short*)(ws + 25165824);      // 16,777,216 B
    unsigned short* kb    = (unsigned short*)(ws + 41943040);      // 16,777,216 B
    unsigned short* vb    = (unsigned short*)(ws + 58720256);      // 16,777,216 B
    unsigned short* ctx   = xb;   // xb dead after QKV GEMM; reuse

    k_cast<<<4096, 256, 0, stream>>>(x, xb, 1048576);
    k_transpose_cast<<<dim3(48, 16), 256, 0, stream>>>(w_qkv, wqkvT, 1024, 3072);
    k_transpose_cast<<<dim3(16, 16), 256, 0, stream>>>(w_out, woutT, 1024, 1024);
    k_gemm_qkv<<<dim3(32, 64), 256, 0, stream>>>(xb, wqkvT, b_qkv, qb, kb, vb, probs);
    k_attn<<<dim3(32, 64), 256, 0, stream>>>(qb, kb, vb, probs, ctx);
    k_gemm_out<<<dim3(8, 64), 256, 0, stream>>>(ctx, woutT, b_out, out);
}

// Round 5
// 386.352 us; speedup vs baseline: 3.5339x; 3.5339x over previous
//
#include <hip/hip_runtime.h>

// MHA forward: B=4, L=2048, E=1024, H=16, D=64, causal, returns (out, attn_probs)

typedef __attribute__((ext_vector_type(8))) short short8;
typedef __attribute__((ext_vector_type(4))) float f32x4;

#define MFMA_BF16(a,b,c) __builtin_amdgcn_mfma_f32_16x16x32_bf16((a),(b),(c),0,0,0)

#define GLDS(gp, lp) __builtin_amdgcn_global_load_lds( \
    (const __attribute__((address_space(1))) unsigned int*)(gp), \
    (__attribute__((address_space(3))) unsigned int*)(lp), 16, 0, 0)

__device__ __forceinline__ unsigned short f2bf(float f) {
    union { float f; unsigned u; } v; v.f = f;
    return (unsigned short)((v.u + 0x7FFFu + ((v.u >> 16) & 1u)) >> 16);
}

// 0.125 (head-dim scale) * log2(e): folded into q at QKV-GEMM epilogue
#define QK_SCALE 0.18033688011112042f

// ---------------- cast x -> bf16 ----------------
__global__ __launch_bounds__(256) void k_cast(const float* __restrict__ src,
                                              unsigned short* __restrict__ dst, int n8) {
    int i = blockIdx.x * 256 + threadIdx.x;
    if (i >= n8) return;
    const float4* s = (const float4*)src + (size_t)i * 2;
    float4 a = s[0], b = s[1];
    short8 o;
    o[0] = f2bf(a.x); o[1] = f2bf(a.y); o[2] = f2bf(a.z); o[3] = f2bf(a.w);
    o[4] = f2bf(b.x); o[5] = f2bf(b.y); o[6] = f2bf(b.z); o[7] = f2bf(b.w);
    ((short8*)dst)[i] = o;
}

// ---------------- transpose + cast weights: src[R][C] f32 -> dst[C][R] bf16 ----------------
__global__ __launch_bounds__(256) void k_transpose_cast(const float* __restrict__ src,
                                                        unsigned short* __restrict__ dst,
                                                        int R, int C) {
    __shared__ unsigned short t[64][72];
    int c0 = blockIdx.x * 64, r0 = blockIdx.y * 64;
    int tid = threadIdx.x;
    int rl = tid >> 2, cs = (tid & 3) * 16;
    const float* sp = src + (size_t)(r0 + rl) * C + c0 + cs;
    #pragma unroll
    for (int j = 0; j < 16; j += 4) {
        float4 v = *(const float4*)(sp + j);
        t[rl][cs + j + 0] = f2bf(v.x);
        t[rl][cs + j + 1] = f2bf(v.y);
        t[rl][cs + j + 2] = f2bf(v.z);
        t[rl][cs + j + 3] = f2bf(v.w);
    }
    __syncthreads();
    int clq = tid >> 2, rs = (tid & 3) * 16;
    short8 o0, o1;
    #pragma unroll
    for (int j = 0; j < 8; ++j) o0[j] = (short)t[rs + j][clq];
    #pragma unroll
    for (int j = 0; j < 8; ++j) o1[j] = (short)t[rs + 8 + j][clq];
    unsigned short* dp = dst + (size_t)(c0 + clq) * R + r0 + rs;
    *(short8*)dp = o0;
    *(short8*)(dp + 8) = o1;
}

// ---------------- QKV GEMM (+overlapped probs upper-triangle zero-fill) ----------------
// blocks x<24: GEMM [8192x1024]x[1024x3072]; blocks x in 24..39: zero-fill
// probs[bh][r][c] for c >= (r/64+1)*64 (region attn never writes).
// Fill is wave-contiguous (1KB/wave) + nontemporal; tiles paired {c, 31-c}
// so every fill block writes the same ~508 KB.
__global__ __launch_bounds__(256) void k_gemm_qkv(
    const unsigned short* __restrict__ A,    // xb [8192][1024]
    const unsigned short* __restrict__ Bt,   // wqkvT [3072][1024]
    const float* __restrict__ bias,          // [3072]
    unsigned short* __restrict__ qb,
    unsigned short* __restrict__ kb,
    unsigned short* __restrict__ vb,
    float* __restrict__ probs)               // [64][2048][2048]
{
    if (blockIdx.x >= 24) {                  // ---- zero-fill path ----
        const int c = blockIdx.x - 24;       // 0..15
        const int bh = blockIdx.y;           // 0..63
        const int tid = threadIdx.x;
        const f32x4 z = {0.f, 0.f, 0.f, 0.f};
        #pragma unroll
        for (int u = 0; u < 2; ++u) {
            const int tt = u == 0 ? c : 31 - c;   // paired: total width const
            const int col0 = (tt + 1) * 64;
            if (col0 >= 2048) continue;
            float* tp = probs + ((size_t)bh * 2048 + tt * 64) * 2048;
            for (int r = 0; r < 64; ++r) {
                float* rp = tp + (size_t)r * 2048;
                for (int cc = col0 + tid * 4; cc < 2048; cc += 1024)
                    __builtin_nontemporal_store(z, (f32x4*)&rp[cc]);
            }
        }
        return;
    }

    __shared__ unsigned short As[128 * 32];
    __shared__ unsigned short Bs[128 * 32];
    const int m0 = blockIdx.y * 128, n0 = blockIdx.x * 128;
    const int tid = threadIdx.x, w = tid >> 6, l = tid & 63;
    const int wm = w >> 1, wn = w & 1;
    const int g = l >> 4, cl = l & 15;
    const int srow = w * 16 + (l >> 2);
    const int soff = (l & 3) * 8;
    f32x4 acc[4][4] = {};

    for (int k0 = 0; k0 < 1024; k0 += 32) {
        __syncthreads();
        #pragma unroll
        for (int c = 0; c < 2; ++c) {
            GLDS(A  + (size_t)(m0 + c * 64 + srow) * 1024 + k0 + soff, &As[(c * 64 + w * 16) * 32]);
            GLDS(Bt + (size_t)(n0 + c * 64 + srow) * 1024 + k0 + soff, &Bs[(c * 64 + w * 16) * 32]);
        }
        __syncthreads();
        short8 af[4], bfr[4];
        #pragma unroll
        for (int i = 0; i < 4; ++i) af[i]  = *(const short8*)&As[(wm * 64 + i * 16 + cl) * 32 + g * 8];
        #pragma unroll
        for (int i = 0; i < 4; ++i) bfr[i] = *(const short8*)&Bs[(wn * 64 + i * 16 + cl) * 32 + g * 8];
        #pragma unroll
        for (int mi = 0; mi < 4; ++mi)
            #pragma unroll
            for (int ni = 0; ni < 4; ++ni)
                acc[mi][ni] = MFMA_BF16(af[mi], bfr[ni], acc[mi][ni]);
    }
    #pragma unroll
    for (int ni = 0; ni < 4; ++ni) {
        int col = n0 + wn * 64 + ni * 16 + cl;
        int which = col >> 10, h = (col >> 6) & 15, d = col & 63;
        unsigned short* dst = which == 0 ? qb : (which == 1 ? kb : vb);
        float bv = bias[col];
        float sc = (which == 0) ? QK_SCALE : 1.0f;   // fold softmax scale into q
        #pragma unroll
        for (int mi = 0; mi < 4; ++mi) {
            #pragma unroll
            for (int i = 0; i < 4; ++i) {
                int row = m0 + wm * 64 + mi * 16 + g * 4 + i;
                int b = row >> 11, ll = row & 2047;
                dst[((size_t)(b * 16 + h) * 2048 + ll) * 64 + d] = f2bf((acc[mi][ni][i] + bv) * sc);
            }
        }
    }
}

// ---------------- out projection GEMM: ctx[8192][1024] x woutT -> out f32 ----------------
__global__ __launch_bounds__(256) void k_gemm_out(
    const unsigned short* __restrict__ A,    // ctx [8192][1024]
    const unsigned short* __restrict__ Bt,   // woutT [1024][1024]
    const float* __restrict__ bias,          // [1024]
    float* __restrict__ out)
{
    __shared__ unsigned short As[128 * 32];
    __shared__ unsigned short Bs[128 * 32];
    const int m0 = blockIdx.y * 128, n0 = blockIdx.x * 128;
    const int tid = threadIdx.x, w = tid >> 6, l = tid & 63;
    const int wm = w >> 1, wn = w & 1;
    const int g = l >> 4, cl = l & 15;
    const int srow = w * 16 + (l >> 2);
    const int soff = (l & 3) * 8;
    f32x4 acc[4][4] = {};

    for (int k0 = 0; k0 < 1024; k0 += 32) {
        __syncthreads();
        #pragma unroll
        for (int c = 0; c < 2; ++c) {
            GLDS(A  + (size_t)(m0 + c * 64 + srow) * 1024 + k0 + soff, &As[(c * 64 + w * 16) * 32]);
            GLDS(Bt + (size_t)(n0 + c * 64 + srow) * 1024 + k0 + soff, &Bs[(c * 64 + w * 16) * 32]);
        }
        __syncthreads();
        short8 af[4], bfr[4];
        #pragma unroll
        for (int i = 0; i < 4; ++i) af[i]  = *(const short8*)&As[(wm * 64 + i * 16 + cl) * 32 + g * 8];
        #pragma unroll
        for (int i = 0; i < 4; ++i) bfr[i] = *(const short8*)&Bs[(wn * 64 + i * 16 + cl) * 32 + g * 8];
        #pragma unroll
        for (int mi = 0; mi < 4; ++mi)
            #pragma unroll
            for (int ni = 0; ni < 4; ++ni)
                acc[mi][ni] = MFMA_BF16(af[mi], bfr[ni], acc[mi][ni]);
    }
    #pragma unroll
    for (int ni = 0; ni < 4; ++ni) {
        int col = n0 + wn * 64 + ni * 16 + cl;
        float bv = bias[col];
        #pragma unroll
        for (int mi = 0; mi < 4; ++mi) {
            #pragma unroll
            for (int i = 0; i < 4; ++i) {
                int row = m0 + wm * 64 + mi * 16 + g * 4 + i;
                out[(size_t)row * 1024 + col] = acc[mi][ni][i] + bv;
            }
        }
    }
}

// ---------------- attention ----------------
// Stage a 64x64 bf16 tile (row-major, stride 64) into linear LDS [64][64] via
// global_load_lds, with the read-side XOR swizzle pre-applied to the GLOBAL
// source (rule #21 both-sides): LDS[row][chunk c] = G[row][c ^ (row&7)].
__device__ __forceinline__ void stage_qk(const unsigned short* gbase,
                                         unsigned short* lds, int w, int l) {
    const int lr = l >> 3;                 // 0..7 (row within the 8-row stripe)
    const int lc = (l & 7) ^ lr;           // pre-swizzled global chunk
    #pragma unroll
    for (int c = 0; c < 2; ++c) {
        const int r0 = (w * 2 + c) * 8;    // stripe base row (wave-uniform)
        GLDS(gbase + (size_t)(r0 + lr) * 64 + (lc << 3), lds + r0 * 64);
    }
}

__global__ __launch_bounds__(256, 4) void k_attn(
    const unsigned short* __restrict__ qb,
    const unsigned short* __restrict__ kb,
    const unsigned short* __restrict__ vb,
    float* __restrict__ probs,               // [64][2048][2048]
    unsigned short* __restrict__ ctx)        // [4][2048][1024] bf16
{
    __shared__ unsigned short Ks[2][64 * 64];    // 16 KB, double-buffered
    __shared__ unsigned short QV[64 * 64];       // 8 KB: Q tile, reused as Vt after frag load
    __shared__ unsigned short Ps[4 * 16 * 64];   // 8 KB, per-wave [16][64] chunk-XOR
    // total 32 KB -> 4 blocks/CU

    // XCD-aware swizzle (2048 blocks % 8 == 0 -> bijective): XCD j serves
    // bh j*8..j*8+7 (K/V working set ~2MB, fits 4MB L2); qt descending so
    // longest blocks launch first.
    const int lid = blockIdx.y * 32 + blockIdx.x;
    const int nl  = (lid & 7) * 256 + (lid >> 3);
    const int qt  = 31 - (nl & 31);          // 0..31
    const int bh  = nl >> 5;                 // 0..63

    const int tid = threadIdx.x;
    const int w = tid >> 6, l = tid & 63;
    const int g = l >> 4, cl = l & 15;

    const unsigned short* Qg = qb + (size_t)bh * (2048 * 64);
    const unsigned short* Kg = kb + (size_t)bh * (2048 * 64);
    const unsigned short* Vg = vb + (size_t)bh * (2048 * 64);

    stage_qk(Qg + (size_t)qt * (64 * 64), QV, w, l);
    stage_qk(Kg, Ks[0], w, l);
    __syncthreads();

    const int qr = w * 16 + cl;              // this lane's Q row for the A-frag
    short8 aq0 = *(const short8*)&QV[qr * 64 + ((g ^ (qr & 7)) << 3)];
    short8 aq1 = *(const short8*)&QV[qr * 64 + (((g + 4) ^ (qr & 7)) << 3)];

    // ---- pass 1: row sums of exp2 (q pre-scaled; no max; reduce deferred) ----
    f32x4 lpart = {0.f, 0.f, 0.f, 0.f};
    for (int kt = 0; kt <= qt; ++kt) {
        const unsigned short* K = Ks[kt & 1];
        if (kt < qt) {
            stage_qk(Kg + (size_t)(kt + 1) * (64 * 64), Ks[(kt & 1) ^ 1], w, l);
            #pragma unroll
            for (int kf = 0; kf < 4; ++kf) {
                int r = kf * 16 + cl;
                short8 b0 = *(const short8*)&K[r * 64 + ((g ^ (r & 7)) << 3)];
                short8 b1 = *(const short8*)&K[r * 64 + (((g + 4) ^ (r & 7)) << 3)];
                f32x4 acc = {0.f, 0.f, 0.f, 0.f};
                acc = MFMA_BF16(aq0, b0, acc);
                acc = MFMA_BF16(aq1, b1, acc);
                #pragma unroll
                for (int i = 0; i < 4; ++i)
                    lpart[i] += __builtin_amdgcn_exp2f(acc[i]);
            }
        } else {
            #pragma unroll
            for (int kf = 0; kf < 4; ++kf) {
                int r = kf * 16 + cl;
                short8 b0 = *(const short8*)&K[r * 64 + ((g ^ (r & 7)) << 3)];
                short8 b1 = *(const short8*)&K[r * 64 + (((g + 4) ^ (r & 7)) << 3)];
                f32x4 acc = {0.f, 0.f, 0.f, 0.f};
                acc = MFMA_BF16(aq0, b0, acc);
                acc = MFMA_BF16(aq1, b1, acc);
                #pragma unroll
                for (int i = 0; i < 4; ++i) {
                    float e = __builtin_amdgcn_exp2f(acc[i]);
                    lpart[i] += (r > w * 16 + g * 4 + i) ? 0.f : e;
                }
            }
        }
        __syncthreads();
    }

    f32x4 lr;   // -log2(rowsum): p = exp2(acc + lr)
    #pragma unroll
    for (int i = 0; i < 4; ++i) {
        float s = lpart[i];
        s += __shfl_xor(s, 1);
        s += __shfl_xor(s, 2);
        s += __shfl_xor(s, 4);
        s += __shfl_xor(s, 8);
        lr[i] = -__log2f(s);
    }

    // ---- pass 2: probs + PV ----
    stage_qk(Kg, Ks[0], w, l);
    // V ownership: thread t holds k-pair (t&31), d-chunk (t>>5).
    const int vkp = tid & 31;
    const int vd0 = (tid >> 5) * 8;
    short8 va  = *(const short8*)(Vg + (size_t)(2 * vkp) * 64 + vd0);
    short8 vb8 = *(const short8*)(Vg + (size_t)(2 * vkp + 1) * 64 + vd0);
    __syncthreads();

    f32x4 cacc[4] = {};
    unsigned int* Vt32 = (unsigned int*)QV;

    for (int kt = 0; kt <= qt; ++kt) {
        const unsigned short* K = Ks[kt & 1];
        const bool last = (kt == qt);
        if (!last) stage_qk(Kg + (size_t)(kt + 1) * (64 * 64), Ks[(kt & 1) ^ 1], w, l);

        // write V(kt) transposed: Vt[d][k], packed u32 (2 k's), 2-way banks
        #pragma unroll
        for (int j = 0; j < 8; ++j) {
            unsigned int pk = (unsigned int)(unsigned short)va[j]
                            | ((unsigned int)(unsigned short)vb8[j] << 16);
            Vt32[(vd0 + j) * 32 + (((vkp >> 2) ^ j) << 2) + (vkp & 3)] = pk;
        }
        if (!last) {  // prefetch V(kt+1); latency hidden under QK phase
            va  = *(const short8*)(Vg + (size_t)((kt + 1) * 64 + 2 * vkp) * 64 + vd0);
            vb8 = *(const short8*)(Vg + (size_t)((kt + 1) * 64 + 2 * vkp + 1) * 64 + vd0);
        }

        // QK + exp2(+lr) + nontemporal probs stores + Ps (bf16, chunk-XOR)
        size_t prow = ((size_t)bh * 2048 + qt * 64 + w * 16 + g * 4) * 2048 + kt * 64;
        #pragma unroll
        for (int kf = 0; kf < 4; ++kf) {
            int r = kf * 16 + cl;
            short8 b0 = *(const short8*)&K[r * 64 + ((g ^ (r & 7)) << 3)];
            short8 b1 = *(const short8*)&K[r * 64 + (((g + 4) ^ (r & 7)) << 3)];
            f32x4 acc = {0.f, 0.f, 0.f, 0.f};
            acc = MFMA_BF16(aq0, b0, acc);
            acc = MFMA_BF16(aq1, b1, acc);
            #pragma unroll
            for (int i = 0; i < 4; ++i) {
                float p = __builtin_amdgcn_exp2f(acc[i] + lr[i]);
                if (last && r > w * 16 + g * 4 + i) p = 0.f;
                __builtin_nontemporal_store(p, &probs[prow + (size_t)i * 2048 + kf * 16 + cl]);
                int rr = g * 4 + i;
                int scol = (((2 * kf + (cl >> 3)) ^ (rr & 7)) << 3) + (cl & 7);
                Ps[(w * 16 + rr) * 64 + scol] = f2bf(p);
            }
        }
        __syncthreads();   // Ps + Vt visible

        #pragma unroll
        for (int kk = 0; kk < 2; ++kk) {
            short8 pa = *(const short8*)&Ps[(w * 16 + cl) * 64 + (((kk * 4 + g) ^ (cl & 7)) << 3)];
            #pragma unroll
            for (int df = 0; df < 4; ++df) {
                int vr = df * 16 + cl;
                short8 vf = *(const short8*)&QV[vr * 64 + (((kk * 4 + g) ^ (vr & 7)) << 3)];
                cacc[df] = MFMA_BF16(pa, vf, cacc[df]);
            }
        }
        __syncthreads();   // PV reads done before next tile's Vt/Ps/Ks writes
    }

    // write context bf16 [B][L][E]  (upper-triangle probs zeros were written
    // by k_gemm_qkv's fill blocks)
    {
        const int b = bh >> 4, h = bh & 15;
        #pragma unroll
        for (int df = 0; df < 4; ++df) {
            #pragma unroll
            for (int i = 0; i < 4; ++i) {
                int row = qt * 64 + w * 16 + g * 4 + i;
                ctx[((size_t)(b * 2048 + row)) * 1024 + h * 64 + df * 16 + cl] = f2bf(cacc[df][i]);
            }
        }
    }
}

extern "C" void kernel_launch(void* const* d_in, const int* in_sizes, int n_in,
                              void* d_out, int out_size, void* d_ws, size_t ws_size,
                              hipStream_t stream) {
    const float* x     = (const float*)d_in[0];
    const float* w_qkv = (const float*)d_in[1];
    const float* b_qkv = (const float*)d_in[2];
    const float* w_out = (const float*)d_in[3];
    const float* b_out = (const float*)d_in[4];

    float* out   = (float*)d_out;
    float* probs = out + (size_t)8192 * 1024;   // out first, then attn_probs

    char* ws = (char*)d_ws;
    unsigned short* xb    = (unsigned short*)(ws);                 // 16,777,216 B
    unsigned short* wqkvT = (unsigned short*)(ws + 16777216);      //  6,291,456 B
    unsigned short* woutT = (unsigned short*)(ws + 23068672);      //  2,097,152 B
    unsigned short* qb    = (unsigned short*)(ws + 25165824);      // 16,777,216 B
    unsigned short* kb    = (unsigned short*)(ws + 41943040);      // 16,777,216 B
    unsigned short* vb    = (unsigned short*)(ws + 58720256);      // 16,777,216 B
    unsigned short* ctx   = xb;   // xb dead after QKV GEMM; reuse

    k_cast<<<4096, 256, 0, stream>>>(x, xb, 1048576);
    k_transpose_cast<<<dim3(48, 16), 256, 0, stream>>>(w_qkv, wqkvT, 1024, 3072);
    k_transpose_cast<<<dim3(16, 16), 256, 0, stream>>>(w_out, woutT, 1024, 1024);
    k_gemm_qkv<<<dim3(40, 64), 256, 0, stream>>>(xb, wqkvT, b_qkv, qb, kb, vb, probs);
    k_attn<<<dim3(32, 64), 256, 0, stream>>>(qb, kb, vb, probs, ctx);
    k_gemm_out<<<dim3(8, 64), 256, 0, stream>>>(ctx, woutT, b_out, out);
}